// Round 1
// baseline (57.908 us; speedup 1.0000x reference)
//
#include <hip/hip_runtime.h>

// anchors: (8192, 8, 768) fp32, flattened to [n=8192 rows][COLS=6144 cols]
// loss = -((2*n*sum(a^2) - 2*dot(colsum, colsum)) / sqrt(768)) / (8*8)

constexpr int COLS   = 6144;       // k * dim_emb = 8 * 768
constexpr int COLS4  = COLS / 4;   // 1536 float4 per row
constexpr int BLK    = 256;
constexpr int STRIPS = COLS4 / BLK;        // 6 column strips
constexpr int ROWS_PER_CHUNK = 64;

__global__ void __launch_bounds__(BLK)
anchor_pass1(const float4* __restrict__ a,
             float* __restrict__ col_sum,   // [COLS]
             float* __restrict__ sum_sq) {  // [1]
    const int col4 = blockIdx.x * BLK + threadIdx.x;   // 0..COLS4-1
    const int row0 = blockIdx.y * ROWS_PER_CHUNK;
    const float4* p = a + (size_t)row0 * COLS4 + col4;

    float4 cs = make_float4(0.f, 0.f, 0.f, 0.f);
    float ssq = 0.f;
    #pragma unroll 8
    for (int r = 0; r < ROWS_PER_CHUNK; ++r) {
        float4 v = p[(size_t)r * COLS4];
        cs.x += v.x; cs.y += v.y; cs.z += v.z; cs.w += v.w;
        ssq = fmaf(v.x, v.x, ssq);
        ssq = fmaf(v.y, v.y, ssq);
        ssq = fmaf(v.z, v.z, ssq);
        ssq = fmaf(v.w, v.w, ssq);
    }

    float* c = col_sum + col4 * 4;
    atomicAdd(c + 0, cs.x);
    atomicAdd(c + 1, cs.y);
    atomicAdd(c + 2, cs.z);
    atomicAdd(c + 3, cs.w);

    // wave (64-lane) reduce of ssq, then cross-wave via LDS, 1 atomic/block
    #pragma unroll
    for (int off = 32; off > 0; off >>= 1)
        ssq += __shfl_down(ssq, off, 64);
    __shared__ float wsum[BLK / 64];
    const int lane = threadIdx.x & 63, wid = threadIdx.x >> 6;
    if (lane == 0) wsum[wid] = ssq;
    __syncthreads();
    if (threadIdx.x == 0) {
        float s = 0.f;
        #pragma unroll
        for (int w = 0; w < BLK / 64; ++w) s += wsum[w];
        atomicAdd(sum_sq, s);
    }
}

__global__ void __launch_bounds__(1024)
anchor_pass2(const float* __restrict__ col_sum,
             const float* __restrict__ sum_sq,
             float* __restrict__ out, int n_rows) {
    float acc = 0.f;
    for (int i = threadIdx.x; i < COLS; i += 1024) {
        float v = col_sum[i];
        acc = fmaf(v, v, acc);
    }
    #pragma unroll
    for (int off = 32; off > 0; off >>= 1)
        acc += __shfl_down(acc, off, 64);
    __shared__ float wsum[1024 / 64];
    const int lane = threadIdx.x & 63, wid = threadIdx.x >> 6;
    if (lane == 0) wsum[wid] = acc;
    __syncthreads();
    if (threadIdx.x == 0) {
        float dot = 0.f;
        #pragma unroll
        for (int w = 0; w < 1024 / 64; ++w) dot += wsum[w];
        double pair = 2.0 * (double)n_rows * (double)(*sum_sq)
                    - 2.0 * (double)dot;
        const double factor = 27.712812921102035;  // sqrt(768)
        out[0] = (float)(-(pair / factor) / 64.0); // k*k = 64
    }
}

extern "C" void kernel_launch(void* const* d_in, const int* in_sizes, int n_in,
                              void* d_out, int out_size, void* d_ws, size_t ws_size,
                              hipStream_t stream) {
    const float4* a = (const float4*)d_in[0];
    float* ws      = (float*)d_ws;          // [0..COLS): col_sum, [COLS]: sum_sq
    float* out     = (float*)d_out;
    const int n_rows = in_sizes[0] / COLS;  // 8192

    hipMemsetAsync(d_ws, 0, (COLS + 1) * sizeof(float), stream);

    dim3 grid(STRIPS, n_rows / ROWS_PER_CHUNK);
    anchor_pass1<<<grid, BLK, 0, stream>>>(a, ws, ws + COLS);
    anchor_pass2<<<1, 1024, 0, stream>>>(ws, ws + COLS, out, n_rows);
}